// Round 4
// baseline (234.763 us; speedup 1.0000x reference)
//
#include <hip/hip_runtime.h>
#include <hip/hip_bf16.h>

// GAT on two 512-node cliques + bipartite cross edges, 5 GATConv layers.
// Edge lists are dense in disguise: "inside" = full clique within each set
// (incl. self-loop), "cross" = full bipartite to the opposite set + self-loop.
//
// Layers 1-4 (heads=128, ch=1): fused kernel per layer, separable softmax:
//   exp(lrelu(s_j+d_i)) = exp(s_j)exp(d_i)        if s_j >= -d_i
//                       = exp(.2 s_j)exp(.2 d_i)  otherwise
// Split set is a prefix of sorted s -> rank (compare-all), scatter, float4
// prefix scan, per-dst binary search + O(1) combine. Final layer (heads=1,
// ch=128) direct (validated round 3). All internal compute f32.
//
// DTYPE: runtime-detected f32 vs bf16 (validated round 3).

typedef __hip_bfloat16 bf16;

__device__ __forceinline__ float b2f(bf16 x) { return __bfloat162float(x); }

__device__ __forceinline__ int detect_bf16(const void* desc1) {
  const unsigned* u = (const unsigned*)desc1;
  int hits = 0;
#pragma unroll 8
  for (int i = 0; i < 256; ++i) {
    unsigned e = (u[i] >> 7) & 0xFFu;
    hits += (e >= 100u && e <= 140u) ? 1 : 0;
  }
  return hits >= 200 ? 1 : 0;
}

__device__ __forceinline__ float load_in(const void* p, int i, int bf) {
  return bf ? b2f(((const bf16*)p)[i]) : ((const float*)p)[i];
}

// ---------------------------------------------------------------- prep ----
__global__ __launch_bounds__(256) void prep_kernel(
    const void* __restrict__ desc1, const void* __restrict__ desc2,
    const void* __restrict__ W1,   const void* __restrict__ as1,
    const void* __restrict__ ad1,  const void* __restrict__ b1,
    const void* __restrict__ W2,   const void* __restrict__ as2,
    const void* __restrict__ ad2,  const void* __restrict__ b2,
    float* __restrict__ xt, float* __restrict__ W1f, float* __restrict__ W2f,
    float* __restrict__ vecs, int* __restrict__ flag) {
  const int bf = detect_bf16(desc1);
  if (blockIdx.x == 0 && threadIdx.x == 0) *flag = bf;
  const int total = 131072 + 16384 + 16384 + 6 * 128;
  for (int idx = blockIdx.x * blockDim.x + threadIdx.x; idx < total;
       idx += gridDim.x * blockDim.x) {
    if (idx < 131072) {
      int n = idx & 1023, c = idx >> 10;
      float v = (n < 512) ? load_in(desc1, n * 128 + c, bf)
                          : load_in(desc2, (n - 512) * 128 + c, bf);
      xt[idx] = v;  // xt[c*1024 + n]
    } else if (idx < 147456) {
      W1f[idx - 131072] = load_in(W1, idx - 131072, bf);
    } else if (idx < 163840) {
      W2f[idx - 147456] = load_in(W2, idx - 147456, bf);
    } else {
      int i = idx - 163840, o = i & 127;
      float v;
      if      (i < 128) v = load_in(as1, o, bf);
      else if (i < 256) v = load_in(ad1, o, bf);
      else if (i < 384) v = load_in(b1, o, bf);
      else if (i < 512) v = load_in(as2, o, bf);
      else if (i < 640) v = load_in(ad2, o, bf);
      else              v = load_in(b2, o, bf);
      vecs[i] = v;
    }
  }
}

// ------------------------------------------------------- fused GAT layer ----
// grid 256 = (S<<7)|hd, 512 threads.  Sources = set S; dst = S (inside) or
// 1-S (cross).  Thread tid owns source node S*512+tid AND dst node D*512+tid.
template <int CROSS>
__global__ __launch_bounds__(512) void layer_kernel(
    const float* __restrict__ xt_in, float* __restrict__ xt_out,
    const float* __restrict__ Wf, const float* __restrict__ vecs) {
  __shared__ float  ss[512];        // unsorted source scores
  __shared__ float  sortedS[512];
  __shared__ float  sortedH[512];
  __shared__ float4 scanA[512];
  __shared__ float4 scanB[512];

  const int tid = threadIdx.x;
  const int hd  = blockIdx.x & 127;
  const int S   = blockIdx.x >> 7;
  const int D   = CROSS ? (1 - S) : S;
  const float a_src = vecs[hd], a_dst = vecs[128 + hd], bias = vecs[256 + hd];

  // Phase 1: h column for this head (src set; dst set too if cross).
  float accSa = 0.f, accSb = 0.f, accDa = 0.f, accDb = 0.f;
#pragma unroll 8
  for (int k = 0; k < 128; k += 2) {
    float w0 = Wf[k * 128 + hd];
    float w1 = Wf[(k + 1) * 128 + hd];
    accSa = fmaf(xt_in[k * 1024 + S * 512 + tid],       w0, accSa);
    accSb = fmaf(xt_in[(k + 1) * 1024 + S * 512 + tid], w1, accSb);
    if (CROSS) {
      accDa = fmaf(xt_in[k * 1024 + D * 512 + tid],       w0, accDa);
      accDb = fmaf(xt_in[(k + 1) * 1024 + D * 512 + tid], w1, accDb);
    }
  }
  const float h_src = accSa + accSb;
  const float h_dst = CROSS ? (accDa + accDb) : h_src;
  const float s_own = h_src * a_src;   // source score of node S*512+tid
  const float d_own = h_dst * a_dst;   // dst score of node D*512+tid
  ss[tid] = s_own;
  __syncthreads();

  // Phase 2: rank by compare-all (stable via index tie-break), scatter.
  {
    int r = 0;
#pragma unroll 8
    for (int j = 0; j < 512; ++j) {
      float sj = ss[j];
      r += (sj < s_own || (sj == s_own && j < tid)) ? 1 : 0;
    }
    sortedS[r] = s_own;
    sortedH[r] = h_src;
  }
  __syncthreads();

  // Phase 3: exp + pack (E2, E2*h, rev(E1), rev(E1*h)).
  {
    float sv = sortedS[tid];
    float hv = sortedH[tid];
    float e1 = __expf(sv), e2 = __expf(0.2f * sv);
    scanA[tid].x = e2;
    scanA[tid].y = e2 * hv;
    scanA[511 - tid].z = e1;
    scanA[511 - tid].w = e1 * hv;
  }
  __syncthreads();

  // Phase 4: inclusive Hillis-Steele scan over 512 float4s (9 steps).
  float4* srcb = scanA;
  float4* dstb = scanB;
  for (int d = 1; d < 512; d <<= 1) {
    float4 v = srcb[tid];
    if (tid >= d) {
      float4 u = srcb[tid - d];
      v.x += u.x; v.y += u.y; v.z += u.z; v.w += u.w;
    }
    dstb[tid] = v;
    __syncthreads();
    float4* t = srcb; srcb = dstb; dstb = t;
  }
  const float4* SC = srcb;  // final inclusive scan

  // Phase 5: this thread's destination: binary search + O(1) combine.
  {
    const float theta = -d_own;
    int k = 0;
#pragma unroll
    for (int s = 512; s > 0; s >>= 1) {
      int nk = k + s;
      if (nk <= 512 && sortedS[nk - 1] < theta) k = nk;
    }
    // [0,k): s < theta -> 0.2-scaled branch; [k,512): full branch.
    float F1 = __expf(d_own), F2 = __expf(0.2f * d_own);
    float P2 = 0.f, P2h = 0.f, S1 = 0.f, S1h = 0.f;
    if (k > 0)   { float4 t4 = SC[k - 1];   P2 = t4.x; P2h = t4.y; }
    if (k < 512) { float4 t4 = SC[511 - k]; S1 = t4.z; S1h = t4.w; }
    float den = F1 * S1 + F2 * P2;
    float num = F1 * S1h + F2 * P2h;
    if (CROSS) {  // self-loop: dst node's own source score (set D)
      float t = h_dst * a_src + d_own;
      float p = __expf(fmaxf(t, 0.2f * t));
      den += p;
      num = fmaf(p, h_dst, num);
    }
    float o = num / (den + 1e-16f) + bias;
    o = (o > 0.f) ? o : expm1f(o);  // ELU
    xt_out[hd * 1024 + D * 512 + tid] = o;
  }
}

// ----------------------------------------------------- final layer: mm2 ----
// grid 512 x 256: 2 rows x 128 cols per block.  h2 = x@W2, s2/d2 row dots.
__global__ __launch_bounds__(256) void mm2_kernel(
    const float* __restrict__ xt_in, const float* __restrict__ W2f,
    const float* __restrict__ vecs, float* __restrict__ h2,
    float* __restrict__ s2, float* __restrict__ d2) {
  __shared__ float rs[256], rd[256];
  const int tid = threadIdx.x;
  const int row = blockIdx.x * 2 + (tid >> 7);
  const int c = tid & 127;
  float acca = 0.f, accb = 0.f;
#pragma unroll 8
  for (int k = 0; k < 128; k += 2) {
    acca = fmaf(xt_in[k * 1024 + row], W2f[k * 128 + c], acca);
    accb = fmaf(xt_in[(k + 1) * 1024 + row], W2f[(k + 1) * 128 + c], accb);
  }
  float acc = acca + accb;
  h2[row * 128 + c] = acc;
  rs[tid] = acc * vecs[384 + c];  // a_src2
  rd[tid] = acc * vecs[512 + c];  // a_dst2
  __syncthreads();
  for (int off = 64; off > 0; off >>= 1) {
    if ((tid & 127) < off) { rs[tid] += rs[tid + off]; rd[tid] += rd[tid + off]; }
    __syncthreads();
  }
  if ((tid & 127) == 0) {
    s2[row] = rs[tid];
    d2[row] = rd[tid];
  }
}

// ---------------------------------------------------- final layer: attn ----
// grid 256 x 512: 4 dst x 128 ch per block.  Direct weighted row-sum.
// Final conv: heads=1, ch=128, concat=False (mean over 1 head = identity),
// no ELU, +b2.  Writes f32 or bf16 per *flag.
__global__ __launch_bounds__(512) void att2_kernel(
    const float* __restrict__ h2, const float* __restrict__ s2,
    const float* __restrict__ d2, const float* __restrict__ vecs,
    void* __restrict__ out, const int* __restrict__ flag) {
  __shared__ float pL[4][512];
  const int tid = threadIdx.x;
  const int dstBase = blockIdx.x * 4;
  const int srcBase = (dstBase < 512) ? 512 : 0;  // cross edges

  for (int e = tid; e < 2048; e += 512) {
    int ld = e >> 9, j = e & 511;
    float t = s2[srcBase + j] + d2[dstBase + ld];
    pL[ld][j] = __expf(fmaxf(t, 0.2f * t));
  }
  __syncthreads();

  const int ld = tid >> 7, c = tid & 127;
  const int i = dstBase + ld;
  float acc = 0.f, den = 0.f;
  const float* hrow = h2 + srcBase * 128 + c;
#pragma unroll 4
  for (int j = 0; j < 512; ++j) {
    float p = pL[ld][j];
    den += p;
    acc = fmaf(p, hrow[j * 128], acc);
  }
  float ts = s2[i] + d2[i];
  float ps = __expf(fmaxf(ts, 0.2f * ts));  // self-loop
  den += ps;
  acc = fmaf(ps, h2[i * 128 + c], acc);
  float o = acc / (den + 1e-16f) + vecs[640 + c];
  if (*flag) ((bf16*)out)[i * 128 + c] = __float2bfloat16(o);
  else       ((float*)out)[i * 128 + c] = o;
}

// ------------------------------------------------------------- launcher ----
extern "C" void kernel_launch(void* const* d_in, const int* in_sizes, int n_in,
                              void* d_out, int out_size, void* d_ws, size_t ws_size,
                              hipStream_t stream) {
  (void)in_sizes; (void)n_in; (void)out_size; (void)ws_size;
  float* ws   = (float*)d_ws;
  float* xtA  = ws;            // 131072
  float* xtB  = ws + 131072;   // 131072
  float* h2   = ws + 262144;   // 131072
  float* W1f  = ws + 393216;   // 16384
  float* W2f  = ws + 409600;   // 16384
  float* vecs = ws + 425984;   // 768
  float* s2   = ws + 426752;   // 1024
  float* d2   = ws + 427776;   // 1024
  int*   flag = (int*)(ws + 428800);

  prep_kernel<<<64, 256, 0, stream>>>(d_in[0], d_in[1], d_in[2], d_in[3],
                                      d_in[4], d_in[5], d_in[6], d_in[7],
                                      d_in[8], d_in[9], xtA, W1f, W2f, vecs, flag);
  layer_kernel<0><<<256, 512, 0, stream>>>(xtA, xtB, W1f, vecs);  // L1 inside
  layer_kernel<1><<<256, 512, 0, stream>>>(xtB, xtA, W1f, vecs);  // L2 cross
  layer_kernel<0><<<256, 512, 0, stream>>>(xtA, xtB, W1f, vecs);  // L3 inside
  layer_kernel<1><<<256, 512, 0, stream>>>(xtB, xtA, W1f, vecs);  // L4 cross
  mm2_kernel<<<512, 256, 0, stream>>>(xtA, W2f, vecs, h2, s2, d2);
  att2_kernel<<<256, 512, 0, stream>>>(h2, s2, d2, vecs, d_out, flag);
}